// Round 4
// baseline (231.699 us; speedup 1.0000x reference)
//
#include <hip/hip_runtime.h>

// LayerNorm(K=128) + Linear(128x128) fused, fp32 in/out, bf16 MFMA inside.
// Round 4: round-3 dataflow, residency fixed: 512-thread blocks (8 waves
// share one 32KB frag-order W'), LDS 67.6KB -> exactly 2 blocks/CU,
// grid=512 -> zero tail, 16 waves/CU. Traffic floor 512 MiB -> ~85us.

#define K_DIM 128
#define N_DIM 128
#define SA_STRIDE 136   // shorts: 272B row stride
#define T_PER_WAVE 8    // 16-row tiles per wave; 8 waves -> 1024 rows/block
#define WAVES 8

typedef __attribute__((ext_vector_type(8))) short bf16x8;
typedef __attribute__((ext_vector_type(4))) float f32x4;

static __device__ __forceinline__ unsigned short f2bf(float f) {
    union { float ff; unsigned int u; } v; v.ff = f;
    const unsigned int u = v.u;
    return (unsigned short)((u + 0x7fffu + ((u >> 16) & 1u)) >> 16);  // RNE
}

// prep: ws[0,32KB) = W' = diag(lnw)*B as bf16 in MFMA A-fragment order
//       slot g = (nt*4+kt)*64 + lane; shorts[r] = W'[nt*16+(lane&15)][kt*32+(lane>>4)*8+r]
//       ws[32KB,+512) = c[n] = sum_k lnb[k]*B[k][n]  (fp32)
__global__ void prep_kernel(const float* __restrict__ lnw, const float* __restrict__ lnb,
                            const float* __restrict__ B, unsigned short* __restrict__ wf,
                            float* __restrict__ c) {
    if (blockIdx.x < 8) {
        const int g  = blockIdx.x * 256 + threadIdx.x;   // 0..2047
        const int l  = g & 63;
        const int kt = (g >> 6) & 3;
        const int nt = g >> 8;
        const int n  = nt * 16 + (l & 15);
        const int k0 = kt * 32 + (l >> 4) * 8;
        union { unsigned short us[8]; int4 i4; } pk;
        #pragma unroll
        for (int r = 0; r < 8; ++r)
            pk.us[r] = f2bf(B[(k0 + r) * N_DIM + n] * lnw[k0 + r]);
        *(int4*)(wf + (size_t)g * 8) = pk.i4;
    } else if (threadIdx.x < N_DIM) {
        const int n = threadIdx.x;
        float acc = 0.f;
        #pragma unroll 8
        for (int k = 0; k < K_DIM; ++k)
            acc += lnb[k] * B[k * N_DIM + n];
        c[n] = acc;
    }
}

__global__ __launch_bounds__(512, 4) void lnlin_kernel(
    const float* __restrict__ x, const unsigned short* __restrict__ wf,
    const float* __restrict__ cg, float* __restrict__ out)
{
    __shared__ __align__(16) unsigned short sWf[2048 * 8];              // 32KB frag-order W'
    __shared__ __align__(16) unsigned short sA[WAVES][16 * SA_STRIDE];  // wave-private x_hat

    const int tid  = threadIdx.x;
    const int wave = tid >> 6;
    const int lane = tid & 63;
    const int h    = lane >> 5;   // half-wave: row parity for loads
    const int s    = lane & 31;   // 16B chunk within row for loads
    const int m    = lane & 15;   // MFMA: row index (D col)
    const int kg   = lane >> 4;   // MFMA: k-group / D row-group

    const size_t waveRow0 = ((size_t)blockIdx.x * WAVES + wave) * (T_PER_WAVE * 16);

    // issue first tile's x loads before staging (independent of LDS)
    const float* xp = x + waveRow0 * K_DIM + s * 4;
    float4 v[8];
    #pragma unroll
    for (int i = 0; i < 8; ++i)
        v[i] = *(const float4*)(xp + (2 * i + h) * K_DIM);

    // stage frag-order W': 4 x (16B coalesced global -> contiguous ds_write_b128)
    #pragma unroll
    for (int q = 0; q < 4; ++q) {
        const int idx = q * 512 + tid;
        *(int4*)(sWf + idx * 8) = *(const int4*)(wf + idx * 8);
    }
    // c kept in registers: lane needs c[nt*16 + kg*4 .. +3] (matches D layout)
    f32x4 c[8];
    #pragma unroll
    for (int nt = 0; nt < 8; ++nt)
        c[nt] = *(const f32x4*)(cg + nt * 16 + kg * 4);
    __syncthreads();   // the ONLY barrier

    unsigned short* sAw = sA[wave];
    float* op = out + waveRow0 * N_DIM;

    for (int t = 0; t < T_PER_WAVE; ++t) {
        // --- LN: half-wave shuffle reduce per row (rows 2i+h), pack bf16 ---
        ushort4 pk[8];
        #pragma unroll
        for (int i = 0; i < 8; ++i) {
            const float4 w4 = v[i];
            float sum = (w4.x + w4.y) + (w4.z + w4.w);
            float sq  = w4.x * w4.x + w4.y * w4.y + w4.z * w4.z + w4.w * w4.w;
            #pragma unroll
            for (int mk = 1; mk < 32; mk <<= 1) {
                sum += __shfl_xor(sum, mk);
                sq  += __shfl_xor(sq,  mk);
            }
            const float mean = sum * 0.0078125f;                       // /128
            const float var  = fmaxf(sq * 0.0078125f - mean * mean, 0.f);
            const float rstd = rsqrtf(var + 1e-5f);
            const float nm   = -mean * rstd;
            pk[i].x = f2bf(w4.x * rstd + nm);
            pk[i].y = f2bf(w4.y * rstd + nm);
            pk[i].z = f2bf(w4.z * rstd + nm);
            pk[i].w = f2bf(w4.w * rstd + nm);
        }

        // --- prefetch next tile (v dead); HBM latency hides under MFMA ---
        if (t + 1 < T_PER_WAVE) {
            const float* xn = xp + (t + 1) * 16 * K_DIM;
            #pragma unroll
            for (int i = 0; i < 8; ++i)
                v[i] = *(const float4*)(xn + (2 * i + h) * K_DIM);
        }

        // --- x_hat -> wave-private LDS (no barrier: same-wave lgkmcnt order) ---
        #pragma unroll
        for (int i = 0; i < 8; ++i)
            *(ushort4*)(sAw + (2 * i + h) * SA_STRIDE + s * 4) = pk[i];

        // --- A-fragments: lane (m,kg) reads row m, k = kt*32+kg*8 ---
        bf16x8 af[4];
        #pragma unroll
        for (int kt = 0; kt < 4; ++kt)
            af[kt] = *(const bf16x8*)(sAw + m * SA_STRIDE + kt * 32 + kg * 8);

        // --- MFMA: A-operand = W' frags (contiguous lane*16+imm reads) ---
        f32x4 acc[8];
        #pragma unroll
        for (int nt = 0; nt < 8; ++nt)
            acc[nt] = c[nt];
        #pragma unroll
        for (int kt = 0; kt < 4; ++kt) {
            #pragma unroll
            for (int nt = 0; nt < 8; ++nt) {
                const bf16x8 bw = *(const bf16x8*)(sWf + ((nt * 4 + kt) * 64 + lane) * 8);
                acc[nt] = __builtin_amdgcn_mfma_f32_16x16x32_bf16(bw, af[kt], acc[nt], 0, 0, 0);
            }
        }

        // --- store: lane owns row m; 4 consecutive n per nt -> float4 ---
        float* o = op + (t * 16 + m) * N_DIM + kg * 4;
        #pragma unroll
        for (int nt = 0; nt < 8; ++nt)
            *(f32x4*)(o + nt * 16) = acc[nt];
    }
}

extern "C" void kernel_launch(void* const* d_in, const int* in_sizes, int n_in,
                              void* d_out, int out_size, void* d_ws, size_t ws_size,
                              hipStream_t stream) {
    const float* x   = (const float*)d_in[0];
    const float* lnw = (const float*)d_in[1];
    const float* lnb = (const float*)d_in[2];
    const float* B   = (const float*)d_in[3];
    float* out = (float*)d_out;

    unsigned short* wf = (unsigned short*)d_ws;
    float* cg = (float*)((char*)d_ws + 32768);

    hipLaunchKernelGGL(prep_kernel, dim3(9), dim3(256), 0, stream, lnw, lnb, B, wf, cg);

    const int M = in_sizes[0] / K_DIM;                       // 524288
    const int grid = M / (WAVES * T_PER_WAVE * 16);          // 512 = exactly 2 blocks/CU
    hipLaunchKernelGGL(lnlin_kernel, dim3(grid), dim3(512), 0, stream, x, wf, cg, out);
}

// Round 5
// 129.298 us; speedup vs baseline: 1.7920x; 1.7920x over previous
//
#include <hip/hip_runtime.h>

// LayerNorm(K=128) + Linear(128x128) fused, fp32 in/out, bf16 MFMA inside.
// Round 5: round-4 geometry (512-thd blocks, 8 waves share 32KB frag-order
// W', grid 512 = exactly 2 blocks/CU, zero tail) with register pressure
// fixed: lb(512,2) -> 128-VGPR cap, c and pk moved out of registers.
// Traffic floor 512 MiB -> ~85us at 6.3 TB/s.

#define K_DIM 128
#define N_DIM 128
#define SA_STRIDE 136   // shorts: 272B row stride (R3 measured conflicts negligible)
#define T_PER_WAVE 8    // 16-row tiles per wave; 8 waves -> 1024 rows/block
#define WAVES 8

typedef __attribute__((ext_vector_type(8))) short bf16x8;
typedef __attribute__((ext_vector_type(4))) float f32x4;

static __device__ __forceinline__ unsigned short f2bf(float f) {
    union { float ff; unsigned int u; } v; v.ff = f;
    const unsigned int u = v.u;
    return (unsigned short)((u + 0x7fffu + ((u >> 16) & 1u)) >> 16);  // RNE
}

// prep: ws[0,32KB) = W' = diag(lnw)*B as bf16 in MFMA A-fragment order
//       slot g = (nt*4+kt)*64 + lane; shorts[r] = W'[nt*16+(lane&15)][kt*32+(lane>>4)*8+r]
//       ws[32KB,+512) = c[n] = sum_k lnb[k]*B[k][n]  (fp32)
__global__ void prep_kernel(const float* __restrict__ lnw, const float* __restrict__ lnb,
                            const float* __restrict__ B, unsigned short* __restrict__ wf,
                            float* __restrict__ c) {
    if (blockIdx.x < 8) {
        const int g  = blockIdx.x * 256 + threadIdx.x;   // 0..2047
        const int l  = g & 63;
        const int kt = (g >> 6) & 3;
        const int nt = g >> 8;
        const int n  = nt * 16 + (l & 15);
        const int k0 = kt * 32 + (l >> 4) * 8;
        union { unsigned short us[8]; int4 i4; } pk;
        #pragma unroll
        for (int r = 0; r < 8; ++r)
            pk.us[r] = f2bf(B[(k0 + r) * N_DIM + n] * lnw[k0 + r]);
        *(int4*)(wf + (size_t)g * 8) = pk.i4;
    } else if (threadIdx.x < N_DIM) {
        const int n = threadIdx.x;
        float acc = 0.f;
        #pragma unroll 8
        for (int k = 0; k < K_DIM; ++k)
            acc += lnb[k] * B[k * N_DIM + n];
        c[n] = acc;
    }
}

__global__ __launch_bounds__(512, 2) void lnlin_kernel(
    const float* __restrict__ x, const unsigned short* __restrict__ wf,
    const float* __restrict__ cg, float* __restrict__ out)
{
    __shared__ __align__(16) unsigned short sWf[2048 * 8];              // 32KB frag-order W'
    __shared__ __align__(16) unsigned short sA[WAVES][16 * SA_STRIDE];  // wave-private x_hat
    __shared__ __align__(16) float sC[N_DIM];                           // bias row

    const int tid  = threadIdx.x;
    const int wave = tid >> 6;
    const int lane = tid & 63;
    const int h    = lane >> 5;   // half-wave: row parity for loads
    const int s    = lane & 31;   // 16B chunk within row for loads
    const int m    = lane & 15;   // MFMA: row index (D col)
    const int kg   = lane >> 4;   // MFMA: k-group / D row-group

    const size_t waveRow0 = ((size_t)blockIdx.x * WAVES + wave) * (T_PER_WAVE * 16);

    // issue first tile's x loads before staging (independent of LDS)
    const float* xp = x + waveRow0 * K_DIM + s * 4;
    float4 v[8];
    #pragma unroll
    for (int i = 0; i < 8; ++i)
        v[i] = *(const float4*)(xp + (2 * i + h) * K_DIM);

    // stage frag-order W' (coalesced 16B -> contiguous ds_write_b128) + bias
    #pragma unroll
    for (int q = 0; q < 4; ++q) {
        const int idx = q * 512 + tid;
        *(int4*)(sWf + idx * 8) = *(const int4*)(wf + idx * 8);
    }
    if (tid < N_DIM) sC[tid] = cg[tid];
    __syncthreads();   // the ONLY barrier

    unsigned short* sAw = sA[wave];
    float* op = out + waveRow0 * N_DIM;

    for (int t = 0; t < T_PER_WAVE; ++t) {
        // --- LN: half-wave shuffle reduce per row (rows 2i+h), pack -> LDS ---
        #pragma unroll
        for (int i = 0; i < 8; ++i) {
            const float4 w4 = v[i];
            float sum = (w4.x + w4.y) + (w4.z + w4.w);
            float sq  = w4.x * w4.x + w4.y * w4.y + w4.z * w4.z + w4.w * w4.w;
            #pragma unroll
            for (int mk = 1; mk < 32; mk <<= 1) {
                sum += __shfl_xor(sum, mk);
                sq  += __shfl_xor(sq,  mk);
            }
            const float mean = sum * 0.0078125f;                       // /128
            const float var  = fmaxf(sq * 0.0078125f - mean * mean, 0.f);
            const float rstd = rsqrtf(var + 1e-5f);
            const float nm   = -mean * rstd;
            ushort4 pk;
            pk.x = f2bf(w4.x * rstd + nm);
            pk.y = f2bf(w4.y * rstd + nm);
            pk.z = f2bf(w4.z * rstd + nm);
            pk.w = f2bf(w4.w * rstd + nm);
            *(ushort4*)(sAw + (2 * i + h) * SA_STRIDE + s * 4) = pk;
        }

        // --- prefetch next tile (v dead); HBM latency hides under MFMA ---
        if (t + 1 < T_PER_WAVE) {
            const float* xn = xp + (t + 1) * 16 * K_DIM;
            #pragma unroll
            for (int i = 0; i < 8; ++i)
                v[i] = *(const float4*)(xn + (2 * i + h) * K_DIM);
        }

        // --- A-fragments: lane (m,kg) reads row m, k = kt*32+kg*8 ---
        bf16x8 af[4];
        #pragma unroll
        for (int kt = 0; kt < 4; ++kt)
            af[kt] = *(const bf16x8*)(sAw + m * SA_STRIDE + kt * 32 + kg * 8);

        // --- acc init from sC (broadcast ds_read, conflict-free) + MFMA ---
        f32x4 acc[8];
        #pragma unroll
        for (int nt = 0; nt < 8; ++nt)
            acc[nt] = *(const f32x4*)&sC[nt * 16 + kg * 4];
        #pragma unroll
        for (int kt = 0; kt < 4; ++kt) {
            #pragma unroll
            for (int nt = 0; nt < 8; ++nt) {
                const bf16x8 bw = *(const bf16x8*)(sWf + ((nt * 4 + kt) * 64 + lane) * 8);
                acc[nt] = __builtin_amdgcn_mfma_f32_16x16x32_bf16(bw, af[kt], acc[nt], 0, 0, 0);
            }
        }

        // --- store: lane owns row m; 4 consecutive n per nt -> float4 ---
        float* o = op + (t * 16 + m) * N_DIM + kg * 4;
        #pragma unroll
        for (int nt = 0; nt < 8; ++nt)
            *(f32x4*)(o + nt * 16) = acc[nt];
    }
}

extern "C" void kernel_launch(void* const* d_in, const int* in_sizes, int n_in,
                              void* d_out, int out_size, void* d_ws, size_t ws_size,
                              hipStream_t stream) {
    const float* x   = (const float*)d_in[0];
    const float* lnw = (const float*)d_in[1];
    const float* lnb = (const float*)d_in[2];
    const float* B   = (const float*)d_in[3];
    float* out = (float*)d_out;

    unsigned short* wf = (unsigned short*)d_ws;
    float* cg = (float*)((char*)d_ws + 32768);

    hipLaunchKernelGGL(prep_kernel, dim3(9), dim3(256), 0, stream, lnw, lnb, B, wf, cg);

    const int M = in_sizes[0] / K_DIM;                       // 524288
    const int grid = M / (WAVES * T_PER_WAVE * 16);          // 512 = exactly 2 blocks/CU
    hipLaunchKernelGGL(lnlin_kernel, dim3(grid), dim3(512), 0, stream, x, wf, cg, out);
}

// Round 8
// 126.049 us; speedup vs baseline: 1.8382x; 1.0258x over previous
//
#include <hip/hip_runtime.h>

// LayerNorm(K=128) + Linear(128x128) fused, fp32 in/out, bf16 MFMA inside.
// Round 8: round-5 structure (512-thd blocks, 8 waves share 32KB frag-order
// W', grid 512 = exactly 2 blocks/CU, barrier-free main loop) + LDS-transposed
// store epilogue (every global store = contiguous 1KB aligned burst).
// r6/r7 bug root-caused: cross-lane LDS write->read inside the epilogue had
// no compiler fence; per-thread alias analysis hoisted stage reads above
// stage writes (SIMT cross-lane comms need a fence even within one wave --
// HW LDS is in-order per wave, the COMPILER isn't). Fences added between
// epilogue write/read phases. Traffic floor 512 MiB -> ~85us.

#define K_DIM 128
#define N_DIM 128
#define SA_STRIDE 136    // shorts: 272B row stride for x_hat staging (16B-aligned)
#define ST_STRIDE 136    // floats: 544B row stride, 16B-aligned; 8*136*4B = 4352B = exact region fit
#define T_PER_WAVE 8     // 16-row tiles per wave; 8 waves -> 1024 rows/block
#define WAVES 8

typedef __attribute__((ext_vector_type(8))) short bf16x8;
typedef __attribute__((ext_vector_type(4))) float f32x4;

static __device__ __forceinline__ unsigned short f2bf(float f) {
    union { float ff; unsigned int u; } v; v.ff = f;
    const unsigned int u = v.u;
    return (unsigned short)((u + 0x7fffu + ((u >> 16) & 1u)) >> 16);  // RNE
}

// prep: ws[0,32KB) = W' = diag(lnw)*B as bf16 in MFMA A-fragment order
//       slot g = (nt*4+kt)*64 + lane; shorts[r] = W'[nt*16+(lane&15)][kt*32+(lane>>4)*8+r]
//       ws[32KB,+512) = c[n] = sum_k lnb[k]*B[k][n]  (fp32)
__global__ void prep_kernel(const float* __restrict__ lnw, const float* __restrict__ lnb,
                            const float* __restrict__ B, unsigned short* __restrict__ wf,
                            float* __restrict__ c) {
    if (blockIdx.x < 8) {
        const int g  = blockIdx.x * 256 + threadIdx.x;   // 0..2047
        const int l  = g & 63;
        const int kt = (g >> 6) & 3;
        const int nt = g >> 8;
        const int n  = nt * 16 + (l & 15);
        const int k0 = kt * 32 + (l >> 4) * 8;
        union { unsigned short us[8]; int4 i4; } pk;
        #pragma unroll
        for (int r = 0; r < 8; ++r)
            pk.us[r] = f2bf(B[(k0 + r) * N_DIM + n] * lnw[k0 + r]);
        *(int4*)(wf + (size_t)g * 8) = pk.i4;
    } else if (threadIdx.x < N_DIM) {
        const int n = threadIdx.x;
        float acc = 0.f;
        #pragma unroll 8
        for (int k = 0; k < K_DIM; ++k)
            acc += lnb[k] * B[k * N_DIM + n];
        c[n] = acc;
    }
}

__global__ __launch_bounds__(512, 2) void lnlin_kernel(
    const float* __restrict__ x, const unsigned short* __restrict__ wf,
    const float* __restrict__ cg, float* __restrict__ out)
{
    __shared__ __align__(16) unsigned short sWf[2048 * 8];              // 32KB frag-order W'
    __shared__ __align__(16) unsigned short sA[WAVES][16 * SA_STRIDE];  // wave-private x_hat / epilogue stage
    __shared__ __align__(16) float sC[N_DIM];                           // bias row

    const int tid  = threadIdx.x;
    const int wave = tid >> 6;
    const int lane = tid & 63;
    const int h    = lane >> 5;   // half-wave: row parity
    const int s    = lane & 31;   // 16B chunk within row
    const int m    = lane & 15;   // MFMA: output row index
    const int kg   = lane >> 4;   // MFMA: k-group / n sub-block

    const size_t waveRow0 = ((size_t)blockIdx.x * WAVES + wave) * (T_PER_WAVE * 16);

    // issue first tile's x loads before staging (independent of LDS)
    const float* xp = x + waveRow0 * K_DIM + s * 4;
    float4 v[8];
    #pragma unroll
    for (int i = 0; i < 8; ++i)
        v[i] = *(const float4*)(xp + (2 * i + h) * K_DIM);

    // stage frag-order W' (coalesced 16B -> contiguous ds_write_b128) + bias
    #pragma unroll
    for (int q = 0; q < 4; ++q) {
        const int idx = q * 512 + tid;
        *(int4*)(sWf + idx * 8) = *(const int4*)(wf + idx * 8);
    }
    if (tid < N_DIM) sC[tid] = cg[tid];
    __syncthreads();   // the ONLY barrier

    unsigned short* sAw = sA[wave];
    float* stage = (float*)sAw;            // [8][ST_STRIDE] f32, 4352B = exact region size
    float* op = out + waveRow0 * N_DIM;

    for (int t = 0; t < T_PER_WAVE; ++t) {
        // --- LN: half-wave shuffle reduce per row (rows 2i+h), pack -> LDS ---
        #pragma unroll
        for (int i = 0; i < 8; ++i) {
            const float4 w4 = v[i];
            float sum = (w4.x + w4.y) + (w4.z + w4.w);
            float sq  = w4.x * w4.x + w4.y * w4.y + w4.z * w4.z + w4.w * w4.w;
            #pragma unroll
            for (int mk = 1; mk < 32; mk <<= 1) {
                sum += __shfl_xor(sum, mk);
                sq  += __shfl_xor(sq,  mk);
            }
            const float mean = sum * 0.0078125f;                       // /128
            const float var  = fmaxf(sq * 0.0078125f - mean * mean, 0.f);
            const float rstd = rsqrtf(var + 1e-5f);
            const float nm   = -mean * rstd;
            ushort4 pk;
            pk.x = f2bf(w4.x * rstd + nm);
            pk.y = f2bf(w4.y * rstd + nm);
            pk.z = f2bf(w4.z * rstd + nm);
            pk.w = f2bf(w4.w * rstd + nm);
            *(ushort4*)(sAw + (2 * i + h) * SA_STRIDE + s * 4) = pk;
        }

        // --- prefetch next tile (v dead); HBM latency hides under MFMA ---
        if (t + 1 < T_PER_WAVE) {
            const float* xn = xp + (t + 1) * 16 * K_DIM;
            #pragma unroll
            for (int i = 0; i < 8; ++i)
                v[i] = *(const float4*)(xn + (2 * i + h) * K_DIM);
        }

        // --- A-fragments: lane (m,kg) reads row m, k = kt*32+kg*8 ---
        // after this, sAw contents are dead -> reusable as epilogue stage
        bf16x8 af[4];
        #pragma unroll
        for (int kt = 0; kt < 4; ++kt)
            af[kt] = *(const bf16x8*)(sAw + m * SA_STRIDE + kt * 32 + kg * 8);

        // --- acc init from sC (broadcast ds_read, conflict-free) + MFMA ---
        f32x4 acc[8];
        #pragma unroll
        for (int nt = 0; nt < 8; ++nt)
            acc[nt] = *(const f32x4*)&sC[nt * 16 + kg * 4];
        #pragma unroll
        for (int kt = 0; kt < 4; ++kt) {
            #pragma unroll
            for (int nt = 0; nt < 8; ++nt) {
                const bf16x8 bw = *(const bf16x8*)(sWf + ((nt * 4 + kt) * 64 + lane) * 8);
                acc[nt] = __builtin_amdgcn_mfma_f32_16x16x32_bf16(bw, af[kt], acc[nt], 0, 0, 0);
            }
        }

        // --- epilogue: transpose acc through wave-private LDS so each global
        //     store is a contiguous, 1KB-aligned 1KB burst (2 full rows).
        //     Cross-lane LDS comms: compiler fences REQUIRED between write
        //     and read phases (HW LDS is in-order per wave; the compiler's
        //     per-thread alias analysis is not). ---
        #pragma unroll
        for (int half = 0; half < 2; ++half) {
            if ((m >> 3) == half) {
                const int lr = m & 7;
                #pragma unroll
                for (int nt = 0; nt < 8; ++nt)
                    *(f32x4*)(stage + lr * ST_STRIDE + nt * 16 + kg * 4) = acc[nt];
            }
            asm volatile("" ::: "memory");   // writes (all lanes) before reads
            #pragma unroll
            for (int j = 0; j < 4; ++j) {
                const int lr = j * 2 + h;
                const f32x4 row = *(const f32x4*)(stage + lr * ST_STRIDE + s * 4);
                *(f32x4*)(op + (size_t)(t * 16 + half * 8 + lr) * N_DIM + s * 4) = row;
            }
            asm volatile("" ::: "memory");   // reads before next half's writes (WAR)
        }
    }
}

extern "C" void kernel_launch(void* const* d_in, const int* in_sizes, int n_in,
                              void* d_out, int out_size, void* d_ws, size_t ws_size,
                              hipStream_t stream) {
    const float* x   = (const float*)d_in[0];
    const float* lnw = (const float*)d_in[1];
    const float* lnb = (const float*)d_in[2];
    const float* B   = (const float*)d_in[3];
    float* out = (float*)d_out;

    unsigned short* wf = (unsigned short*)d_ws;
    float* cg = (float*)((char*)d_ws + 32768);

    hipLaunchKernelGGL(prep_kernel, dim3(9), dim3(256), 0, stream, lnw, lnb, B, wf, cg);

    const int M = in_sizes[0] / K_DIM;                       // 524288
    const int grid = M / (WAVES * T_PER_WAVE * 16);          // 512 = exactly 2 blocks/CU
    hipLaunchKernelGGL(lnlin_kernel, dim3(grid), dim3(512), 0, stream, x, wf, cg, out);
}

// Round 9
// 121.043 us; speedup vs baseline: 1.9142x; 1.0414x over previous
//
#include <hip/hip_runtime.h>

// LayerNorm(K=128) + Linear(128x128) fused, fp32 in/out, bf16 MFMA inside.
// Round 9: normalize AFTER the GEMM. LN is per-row affine and GEMM is linear:
//   y = rstd*(x@W') - rstd*mu*colsum(W') + c
// so we MFMA raw-bf16 x against W', get row sums via mfma(ones, af) (free,
// per-lane) and row sumsq via the Gram trick mfma(af, af) (diag, 1 bpermute),
// then apply a per-element FMA epilogue. This deletes the 80-bpermute 5-round
// serial shuffle reduction per tile (r3 counters: waves stalled ~95%,
// VALUBusy 10% -> lgkmcnt-serial LN chain was pacing us, not HBM).
// Structure otherwise = r8: 512-thd blocks, 8 waves share 32KB frag-order W',
// grid 512 = exactly 2 blocks/CU, barrier-free main loop, LDS-burst stores.

#define K_DIM 128
#define N_DIM 128
#define SA_STRIDE 136    // shorts: 272B row stride for x staging (16B-aligned)
#define ST_STRIDE 136    // floats: 544B epilogue stage stride, 16B-aligned
#define T_PER_WAVE 8     // 16-row tiles per wave; 8 waves -> 1024 rows/block
#define WAVES 8

typedef __attribute__((ext_vector_type(8))) short bf16x8;
typedef __attribute__((ext_vector_type(4))) float f32x4;

static __device__ __forceinline__ unsigned short f2bf(float f) {
    union { float ff; unsigned int u; } v; v.ff = f;
    const unsigned int u = v.u;
    return (unsigned short)((u + 0x7fffu + ((u >> 16) & 1u)) >> 16);  // RNE
}

// prep: ws[0,32KB)      = W' = diag(lnw)*B, bf16, MFMA A-frag order
//       ws[32KB,+512)   = c[n]  = sum_k lnb[k]*B[k][n]   (fp32)
//       ws[32.5KB,+512) = w1[n] = sum_k lnw[k]*B[k][n]   (fp32, colsum of W')
__global__ void prep_kernel(const float* __restrict__ lnw, const float* __restrict__ lnb,
                            const float* __restrict__ B, unsigned short* __restrict__ wf,
                            float* __restrict__ c, float* __restrict__ w1) {
    if (blockIdx.x < 8) {
        const int g  = blockIdx.x * 256 + threadIdx.x;   // 0..2047
        const int l  = g & 63;
        const int kt = (g >> 6) & 3;
        const int nt = g >> 8;
        const int n  = nt * 16 + (l & 15);
        const int k0 = kt * 32 + (l >> 4) * 8;
        union { unsigned short us[8]; int4 i4; } pk;
        #pragma unroll
        for (int r = 0; r < 8; ++r)
            pk.us[r] = f2bf(B[(k0 + r) * N_DIM + n] * lnw[k0 + r]);
        *(int4*)(wf + (size_t)g * 8) = pk.i4;
    } else {
        const int tid = threadIdx.x;
        if (tid < N_DIM) {
            float acc = 0.f;
            #pragma unroll 8
            for (int k = 0; k < K_DIM; ++k) acc += lnb[k] * B[k * N_DIM + tid];
            c[tid] = acc;
        } else if (tid < 2 * N_DIM) {
            const int n = tid - N_DIM;
            float acc = 0.f;
            #pragma unroll 8
            for (int k = 0; k < K_DIM; ++k) acc += lnw[k] * B[k * N_DIM + n];
            w1[n] = acc;
        }
    }
}

__global__ __launch_bounds__(512, 2) void lnlin_kernel(
    const float* __restrict__ x, const unsigned short* __restrict__ wf,
    const float* __restrict__ cg, const float* __restrict__ w1g,
    float* __restrict__ out)
{
    __shared__ __align__(16) unsigned short sWf[2048 * 8];              // 32KB frag-order W'
    __shared__ __align__(16) unsigned short sA[WAVES][16 * SA_STRIDE];  // wave-private raw-x bf16 / epilogue stage
    __shared__ __align__(16) float sC[N_DIM];                           // c row
    __shared__ __align__(16) float sW1[N_DIM];                          // colsum(W') row

    const int tid  = threadIdx.x;
    const int wave = tid >> 6;
    const int lane = tid & 63;
    const int h    = lane >> 5;   // half-wave: row parity
    const int s    = lane & 31;   // 16B chunk within row
    const int m    = lane & 15;   // MFMA: output row index
    const int kg   = lane >> 4;   // MFMA: k-group / n sub-block

    const size_t waveRow0 = ((size_t)blockIdx.x * WAVES + wave) * (T_PER_WAVE * 16);

    // issue first tile's x loads before staging (independent of LDS)
    const float* xp = x + waveRow0 * K_DIM + s * 4;
    float4 v[8];
    #pragma unroll
    for (int i = 0; i < 8; ++i)
        v[i] = *(const float4*)(xp + (2 * i + h) * K_DIM);

    // stage frag-order W' (coalesced 16B -> contiguous ds_write_b128) + c + w1
    #pragma unroll
    for (int q = 0; q < 4; ++q) {
        const int idx = q * 512 + tid;
        *(int4*)(sWf + idx * 8) = *(const int4*)(wf + idx * 8);
    }
    if (tid < N_DIM) sC[tid] = cg[tid];
    else if (tid < 2 * N_DIM) sW1[tid - N_DIM] = w1g[tid - N_DIM];
    __syncthreads();   // the ONLY barrier

    // ones fragment for row-sum MFMA
    union { unsigned short u[8]; bf16x8 f; } onesu;
    #pragma unroll
    for (int r = 0; r < 8; ++r) onesu.u[r] = 0x3F80;   // bf16 1.0
    const bf16x8 ones = onesu.f;

    unsigned short* sAw = sA[wave];
    float* stage = (float*)sAw;            // [8][ST_STRIDE] f32, 4352B region
    float* op = out + waveRow0 * N_DIM;

    for (int t = 0; t < T_PER_WAVE; ++t) {
        // --- pack RAW x -> bf16 -> LDS (no stats dependency: starts on load arrival) ---
        #pragma unroll
        for (int i = 0; i < 8; ++i) {
            const float4 w4 = v[i];
            ushort4 pk;
            pk.x = f2bf(w4.x); pk.y = f2bf(w4.y);
            pk.z = f2bf(w4.z); pk.w = f2bf(w4.w);
            *(ushort4*)(sAw + (2 * i + h) * SA_STRIDE + s * 4) = pk;
        }

        // --- prefetch next tile (v dead now) ---
        if (t + 1 < T_PER_WAVE) {
            const float* xn = xp + (t + 1) * 16 * K_DIM;
            #pragma unroll
            for (int i = 0; i < 8; ++i)
                v[i] = *(const float4*)(xn + (2 * i + h) * K_DIM);
        }

        // cross-lane LDS write->read: compiler fence (per-thread AA would reorder)
        asm volatile("" ::: "memory");

        // --- A-fragments: lane (m,kg) reads row m, k = kt*32+kg*8 ---
        bf16x8 af[4];
        #pragma unroll
        for (int kt = 0; kt < 4; ++kt)
            af[kt] = *(const bf16x8*)(sAw + m * SA_STRIDE + kt * 32 + kg * 8);

        // --- MFMA: G = x@W' (8 n-tiles) + row-sum (ones) + Gram (sumsq diag) ---
        f32x4 acc[8] = {};
        f32x4 asum = {0.f, 0.f, 0.f, 0.f};
        f32x4 gram = {0.f, 0.f, 0.f, 0.f};
        #pragma unroll
        for (int kt = 0; kt < 4; ++kt) {
            asum = __builtin_amdgcn_mfma_f32_16x16x32_bf16(ones, af[kt], asum, 0, 0, 0);
            gram = __builtin_amdgcn_mfma_f32_16x16x32_bf16(af[kt], af[kt], gram, 0, 0, 0);
            #pragma unroll
            for (int nt = 0; nt < 8; ++nt) {
                const bf16x8 bw = *(const bf16x8*)(sWf + ((nt * 4 + kt) * 64 + lane) * 8);
                acc[nt] = __builtin_amdgcn_mfma_f32_16x16x32_bf16(bw, af[kt], acc[nt], 0, 0, 0);
            }
        }

        // --- row stats: sum is per-lane free; sumsq = Gram diag via 1 bpermute ---
        // gram layout: lane(p,kg) reg i = Gram[p][kg*4+i]; diag for row p lives in
        // lane ((p>>2)*16 + p), reg (p&3). Every lane exposes its candidate reg,
        // then each lane pulls from its row's diag holder.
        const int msel = m & 3;
        const float dval = (m & 2) ? ((m & 1) ? gram[3] : gram[2])
                                   : ((m & 1) ? gram[1] : gram[0]);
        const float ss   = __shfl(dval, ((m >> 2) << 4) | m);
        const float sum  = asum[0];
        const float mean = sum * 0.0078125f;                          // /128
        const float var  = fmaxf(ss * 0.0078125f - mean * mean, 0.f);
        const float a    = rsqrtf(var + 1e-5f);                       // rstd
        const float b    = -a * mean;
        (void)msel;

        // --- scale: y = a*G + b*w1 + c (broadcast ds_reads, conflict-free) ---
        #pragma unroll
        for (int nt = 0; nt < 8; ++nt) {
            const f32x4 w1v = *(const f32x4*)&sW1[nt * 16 + kg * 4];
            const f32x4 cv  = *(const f32x4*)&sC [nt * 16 + kg * 4];
            #pragma unroll
            for (int i = 0; i < 4; ++i)
                acc[nt][i] = fmaf(a, acc[nt][i], fmaf(b, w1v[i], cv[i]));
        }

        // --- epilogue: transpose acc through wave-private LDS -> 1KB bursts ---
        #pragma unroll
        for (int half = 0; half < 2; ++half) {
            if ((m >> 3) == half) {
                const int lr = m & 7;
                #pragma unroll
                for (int nt = 0; nt < 8; ++nt)
                    *(f32x4*)(stage + lr * ST_STRIDE + nt * 16 + kg * 4) = acc[nt];
            }
            asm volatile("" ::: "memory");   // writes (all lanes) before reads
            #pragma unroll
            for (int j = 0; j < 4; ++j) {
                const int lr = j * 2 + h;
                const f32x4 row = *(const f32x4*)(stage + lr * ST_STRIDE + s * 4);
                *(f32x4*)(op + (size_t)(t * 16 + half * 8 + lr) * N_DIM + s * 4) = row;
            }
            asm volatile("" ::: "memory");   // reads before next writes (WAR)
        }
    }
}

extern "C" void kernel_launch(void* const* d_in, const int* in_sizes, int n_in,
                              void* d_out, int out_size, void* d_ws, size_t ws_size,
                              hipStream_t stream) {
    const float* x   = (const float*)d_in[0];
    const float* lnw = (const float*)d_in[1];
    const float* lnb = (const float*)d_in[2];
    const float* B   = (const float*)d_in[3];
    float* out = (float*)d_out;

    unsigned short* wf = (unsigned short*)d_ws;
    float* cg  = (float*)((char*)d_ws + 32768);
    float* w1g = (float*)((char*)d_ws + 32768 + 512);

    hipLaunchKernelGGL(prep_kernel, dim3(9), dim3(256), 0, stream, lnw, lnb, B, wf, cg, w1g);

    const int M = in_sizes[0] / K_DIM;                       // 524288
    const int grid = M / (WAVES * T_PER_WAVE * 16);          // 512 = exactly 2 blocks/CU
    hipLaunchKernelGGL(lnlin_kernel, dim3(grid), dim3(512), 0, stream, x, wf, cg, w1g, out);
}

// Round 11
// 116.622 us; speedup vs baseline: 1.9868x; 1.0379x over previous
//
#include <hip/hip_runtime.h>

// LayerNorm(K=128) + Linear(128x128) fused, fp32 in/out, bf16 MFMA inside.
// Round 11: r10 fixed for compile -- __builtin_nontemporal_load requires a
// clang ext_vector pointer, not HIP_vector_type<float,4>; x loads now use
// f32x4. Otherwise identical to r10: nontemporal x loads + out stores to
// stop 512MiB zero-reuse stream from thrashing the 32MiB XCD L2s.
// Baseline r9: 121.0us, absmax 0.03125.

#define K_DIM 128
#define N_DIM 128
#define SA_STRIDE 136    // shorts: 272B row stride for x staging (16B-aligned)
#define ST_STRIDE 136    // floats: 544B epilogue stage stride, 16B-aligned
#define T_PER_WAVE 8     // 16-row tiles per wave; 8 waves -> 1024 rows/block
#define WAVES 8

typedef __attribute__((ext_vector_type(8))) short bf16x8;
typedef __attribute__((ext_vector_type(4))) float f32x4;

static __device__ __forceinline__ unsigned short f2bf(float f) {
    union { float ff; unsigned int u; } v; v.ff = f;
    const unsigned int u = v.u;
    return (unsigned short)((u + 0x7fffu + ((u >> 16) & 1u)) >> 16);  // RNE
}

// prep: ws[0,32KB)      = W' = diag(lnw)*B, bf16, MFMA A-frag order
//       ws[32KB,+512)   = c[n]  = sum_k lnb[k]*B[k][n]   (fp32)
//       ws[32.5KB,+512) = w1[n] = sum_k lnw[k]*B[k][n]   (fp32, colsum of W')
__global__ void prep_kernel(const float* __restrict__ lnw, const float* __restrict__ lnb,
                            const float* __restrict__ B, unsigned short* __restrict__ wf,
                            float* __restrict__ c, float* __restrict__ w1) {
    if (blockIdx.x < 8) {
        const int g  = blockIdx.x * 256 + threadIdx.x;   // 0..2047
        const int l  = g & 63;
        const int kt = (g >> 6) & 3;
        const int nt = g >> 8;
        const int n  = nt * 16 + (l & 15);
        const int k0 = kt * 32 + (l >> 4) * 8;
        union { unsigned short us[8]; int4 i4; } pk;
        #pragma unroll
        for (int r = 0; r < 8; ++r)
            pk.us[r] = f2bf(B[(k0 + r) * N_DIM + n] * lnw[k0 + r]);
        *(int4*)(wf + (size_t)g * 8) = pk.i4;
    } else {
        const int tid = threadIdx.x;
        if (tid < N_DIM) {
            float acc = 0.f;
            #pragma unroll 8
            for (int k = 0; k < K_DIM; ++k) acc += lnb[k] * B[k * N_DIM + tid];
            c[tid] = acc;
        } else if (tid < 2 * N_DIM) {
            const int n = tid - N_DIM;
            float acc = 0.f;
            #pragma unroll 8
            for (int k = 0; k < K_DIM; ++k) acc += lnw[k] * B[k * N_DIM + n];
            w1[n] = acc;
        }
    }
}

__global__ __launch_bounds__(512, 2) void lnlin_kernel(
    const float* __restrict__ x, const unsigned short* __restrict__ wf,
    const float* __restrict__ cg, const float* __restrict__ w1g,
    float* __restrict__ out)
{
    __shared__ __align__(16) unsigned short sWf[2048 * 8];              // 32KB frag-order W'
    __shared__ __align__(16) unsigned short sA[WAVES][16 * SA_STRIDE];  // wave-private raw-x bf16 / epilogue stage
    __shared__ __align__(16) float sC[N_DIM];                           // c row
    __shared__ __align__(16) float sW1[N_DIM];                          // colsum(W') row

    const int tid  = threadIdx.x;
    const int wave = tid >> 6;
    const int lane = tid & 63;
    const int h    = lane >> 5;   // half-wave: row parity
    const int s    = lane & 31;   // 16B chunk within row
    const int m    = lane & 15;   // MFMA: output row index
    const int kg   = lane >> 4;   // MFMA: k-group / n sub-block

    const size_t waveRow0 = ((size_t)blockIdx.x * WAVES + wave) * (T_PER_WAVE * 16);

    // issue first tile's x loads before staging (independent of LDS); nt: zero reuse
    const f32x4* xp = (const f32x4*)(x + waveRow0 * K_DIM) + s;
    f32x4 v[8];
    #pragma unroll
    for (int i = 0; i < 8; ++i)
        v[i] = __builtin_nontemporal_load(xp + (2 * i + h) * (K_DIM / 4));

    // stage frag-order W' (coalesced 16B -> contiguous ds_write_b128) + c + w1
    #pragma unroll
    for (int q = 0; q < 4; ++q) {
        const int idx = q * 512 + tid;
        *(int4*)(sWf + idx * 8) = *(const int4*)(wf + idx * 8);
    }
    if (tid < N_DIM) sC[tid] = cg[tid];
    else if (tid < 2 * N_DIM) sW1[tid - N_DIM] = w1g[tid - N_DIM];
    __syncthreads();   // the ONLY barrier

    // ones fragment for row-sum MFMA
    union { unsigned short u[8]; bf16x8 f; } onesu;
    #pragma unroll
    for (int r = 0; r < 8; ++r) onesu.u[r] = 0x3F80;   // bf16 1.0
    const bf16x8 ones = onesu.f;

    unsigned short* sAw = sA[wave];
    float* stage = (float*)sAw;            // [8][ST_STRIDE] f32, 4352B region
    float* op = out + waveRow0 * N_DIM;

    for (int t = 0; t < T_PER_WAVE; ++t) {
        // --- pack RAW x -> bf16 -> LDS (no stats dependency) ---
        #pragma unroll
        for (int i = 0; i < 8; ++i) {
            const f32x4 w4 = v[i];
            ushort4 pk;
            pk.x = f2bf(w4[0]); pk.y = f2bf(w4[1]);
            pk.z = f2bf(w4[2]); pk.w = f2bf(w4[3]);
            *(ushort4*)(sAw + (2 * i + h) * SA_STRIDE + s * 4) = pk;
        }

        // --- prefetch next tile (v dead now); nt loads ---
        if (t + 1 < T_PER_WAVE) {
            const f32x4* xn = xp + (size_t)(t + 1) * 16 * (K_DIM / 4);
            #pragma unroll
            for (int i = 0; i < 8; ++i)
                v[i] = __builtin_nontemporal_load(xn + (2 * i + h) * (K_DIM / 4));
        }

        // cross-lane LDS write->read: compiler fence (per-thread AA would reorder)
        asm volatile("" ::: "memory");

        // --- A-fragments: lane (m,kg) reads row m, k = kt*32+kg*8 ---
        bf16x8 af[4];
        #pragma unroll
        for (int kt = 0; kt < 4; ++kt)
            af[kt] = *(const bf16x8*)(sAw + m * SA_STRIDE + kt * 32 + kg * 8);

        // --- MFMA: G = x@W' (8 n-tiles) + row-sum (ones) + Gram (sumsq diag) ---
        f32x4 acc[8] = {};
        f32x4 asum = {0.f, 0.f, 0.f, 0.f};
        f32x4 gram = {0.f, 0.f, 0.f, 0.f};
        #pragma unroll
        for (int kt = 0; kt < 4; ++kt) {
            asum = __builtin_amdgcn_mfma_f32_16x16x32_bf16(ones, af[kt], asum, 0, 0, 0);
            gram = __builtin_amdgcn_mfma_f32_16x16x32_bf16(af[kt], af[kt], gram, 0, 0, 0);
            #pragma unroll
            for (int nt = 0; nt < 8; ++nt) {
                const bf16x8 bw = *(const bf16x8*)(sWf + ((nt * 4 + kt) * 64 + lane) * 8);
                acc[nt] = __builtin_amdgcn_mfma_f32_16x16x32_bf16(bw, af[kt], acc[nt], 0, 0, 0);
            }
        }

        // --- row stats: sum per-lane free; sumsq = Gram diag via 1 shuffle ---
        const float dval = (m & 2) ? ((m & 1) ? gram[3] : gram[2])
                                   : ((m & 1) ? gram[1] : gram[0]);
        const float ss   = __shfl(dval, ((m >> 2) << 4) | m);
        const float sum  = asum[0];
        const float mean = sum * 0.0078125f;                          // /128
        const float var  = fmaxf(ss * 0.0078125f - mean * mean, 0.f);
        const float a    = rsqrtf(var + 1e-5f);                       // rstd
        const float b    = -a * mean;

        // --- scale: y = a*G + b*w1 + c (broadcast ds_reads, conflict-free) ---
        #pragma unroll
        for (int nt = 0; nt < 8; ++nt) {
            const f32x4 w1v = *(const f32x4*)&sW1[nt * 16 + kg * 4];
            const f32x4 cv  = *(const f32x4*)&sC [nt * 16 + kg * 4];
            #pragma unroll
            for (int i = 0; i < 4; ++i)
                acc[nt][i] = fmaf(a, acc[nt][i], fmaf(b, w1v[i], cv[i]));
        }

        // --- epilogue: transpose acc through wave-private LDS -> 1KB bursts,
        //     nontemporal stores (out is never re-read) ---
        #pragma unroll
        for (int half = 0; half < 2; ++half) {
            if ((m >> 3) == half) {
                const int lr = m & 7;
                #pragma unroll
                for (int nt = 0; nt < 8; ++nt)
                    *(f32x4*)(stage + lr * ST_STRIDE + nt * 16 + kg * 4) = acc[nt];
            }
            asm volatile("" ::: "memory");   // writes (all lanes) before reads
            #pragma unroll
            for (int j = 0; j < 4; ++j) {
                const int lr = j * 2 + h;
                const f32x4 row = *(const f32x4*)(stage + lr * ST_STRIDE + s * 4);
                __builtin_nontemporal_store(row,
                    (f32x4*)(op + (size_t)(t * 16 + half * 8 + lr) * N_DIM + s * 4));
            }
            asm volatile("" ::: "memory");   // reads before next writes (WAR)
        }
    }
}

extern "C" void kernel_launch(void* const* d_in, const int* in_sizes, int n_in,
                              void* d_out, int out_size, void* d_ws, size_t ws_size,
                              hipStream_t stream) {
    const float* x   = (const float*)d_in[0];
    const float* lnw = (const float*)d_in[1];
    const float* lnb = (const float*)d_in[2];
    const float* B   = (const float*)d_in[3];
    float* out = (float*)d_out;

    unsigned short* wf = (unsigned short*)d_ws;
    float* cg  = (float*)((char*)d_ws + 32768);
    float* w1g = (float*)((char*)d_ws + 32768 + 512);

    hipLaunchKernelGGL(prep_kernel, dim3(9), dim3(256), 0, stream, lnw, lnb, B, wf, cg, w1g);

    const int M = in_sizes[0] / K_DIM;                       // 524288
    const int grid = M / (WAVES * T_PER_WAVE * 16);          // 512 = exactly 2 blocks/CU
    hipLaunchKernelGGL(lnlin_kernel, dim3(grid), dim3(512), 0, stream, x, wf, cg, w1g, out);
}

// Round 12
// 112.735 us; speedup vs baseline: 2.0553x; 1.0345x over previous
//
#include <hip/hip_runtime.h>

// LayerNorm(K=128) + Linear(128x128) fused, fp32 in/out, bf16 MFMA inside.
// Round 12: r11 main kernel UNCHANGED (116.6us, absmax 0.03125). Prep kernel
// parallelized: the old c/w1 path was one block running a 128-iter dependent
// L2-latency loop (~4us) + launch overhead -- a serial prologue inside the
// timed graph. New prep: 8 blocks; each thread reuses its W'-transpose B
// loads to accumulate partial c = lnb^T B and w1 = colsum(W'), reduced via
// LDS. Prep ~1-2us. Main kernel: nontemporal streaming, barrier-free loop,
// frag-order W', LDS-burst stores.

#define K_DIM 128
#define N_DIM 128
#define SA_STRIDE 136    // shorts: 272B row stride for x staging (16B-aligned)
#define ST_STRIDE 136    // floats: 544B epilogue stage stride, 16B-aligned
#define T_PER_WAVE 8     // 16-row tiles per wave; 8 waves -> 1024 rows/block
#define WAVES 8

typedef __attribute__((ext_vector_type(8))) short bf16x8;
typedef __attribute__((ext_vector_type(4))) float f32x4;

static __device__ __forceinline__ unsigned short f2bf(float f) {
    union { float ff; unsigned int u; } v; v.ff = f;
    const unsigned int u = v.u;
    return (unsigned short)((u + 0x7fffu + ((u >> 16) & 1u)) >> 16);  // RNE
}

// prep (8 blocks): ws[0,32KB)      = W' = diag(lnw)*B, bf16, MFMA A-frag order
//                  ws[32KB,+512)   = c[n]  = sum_k lnb[k]*B[k][n]   (fp32)
//                  ws[32.5KB,+512) = w1[n] = sum_k lnw[k]*B[k][n]   (fp32)
// block b owns n in [16b,16b+16): same loads feed wf + partial c/w1 sums.
__global__ void prep_kernel(const float* __restrict__ lnw, const float* __restrict__ lnb,
                            const float* __restrict__ B, unsigned short* __restrict__ wf,
                            float* __restrict__ c, float* __restrict__ w1) {
    __shared__ float pc[16][17];
    __shared__ float pw[16][17];
    const int tid = threadIdx.x;
    const int l   = tid & 63;
    const int kt  = tid >> 6;            // 0..3
    const int b   = blockIdx.x;          // 0..7 == nt
    const int n16 = l & 15;
    const int n   = b * 16 + n16;
    const int k0  = kt * 32 + (l >> 4) * 8;
    const int g   = b * 256 + tid;       // wf slot, same mapping as before

    union { unsigned short us[8]; int4 i4; } pk;
    float cacc = 0.f, wacc = 0.f;
    #pragma unroll
    for (int r = 0; r < 8; ++r) {
        const float bv = B[(k0 + r) * N_DIM + n];
        const float wb = bv * lnw[k0 + r];
        pk.us[r] = f2bf(wb);
        cacc += lnb[k0 + r] * bv;
        wacc += wb;
    }
    *(int4*)(wf + (size_t)g * 8) = pk.i4;

    pc[kt * 4 + (l >> 4)][n16] = cacc;
    pw[kt * 4 + (l >> 4)][n16] = wacc;
    __syncthreads();
    if (tid < 32) {
        const int nn = tid & 15;
        float s = 0.f;
        if (tid < 16) {
            #pragma unroll
            for (int q = 0; q < 16; ++q) s += pc[q][nn];
            c[b * 16 + nn] = s;
        } else {
            #pragma unroll
            for (int q = 0; q < 16; ++q) s += pw[q][nn];
            w1[b * 16 + nn] = s;
        }
    }
}

__global__ __launch_bounds__(512, 2) void lnlin_kernel(
    const float* __restrict__ x, const unsigned short* __restrict__ wf,
    const float* __restrict__ cg, const float* __restrict__ w1g,
    float* __restrict__ out)
{
    __shared__ __align__(16) unsigned short sWf[2048 * 8];              // 32KB frag-order W'
    __shared__ __align__(16) unsigned short sA[WAVES][16 * SA_STRIDE];  // wave-private raw-x bf16 / epilogue stage
    __shared__ __align__(16) float sC[N_DIM];                           // c row
    __shared__ __align__(16) float sW1[N_DIM];                          // colsum(W') row

    const int tid  = threadIdx.x;
    const int wave = tid >> 6;
    const int lane = tid & 63;
    const int h    = lane >> 5;   // half-wave: row parity
    const int s    = lane & 31;   // 16B chunk within row
    const int m    = lane & 15;   // MFMA: output row index
    const int kg   = lane >> 4;   // MFMA: k-group / n sub-block

    const size_t waveRow0 = ((size_t)blockIdx.x * WAVES + wave) * (T_PER_WAVE * 16);

    // issue first tile's x loads before staging (independent of LDS); nt: zero reuse
    const f32x4* xp = (const f32x4*)(x + waveRow0 * K_DIM) + s;
    f32x4 v[8];
    #pragma unroll
    for (int i = 0; i < 8; ++i)
        v[i] = __builtin_nontemporal_load(xp + (2 * i + h) * (K_DIM / 4));

    // stage frag-order W' (coalesced 16B -> contiguous ds_write_b128) + c + w1
    #pragma unroll
    for (int q = 0; q < 4; ++q) {
        const int idx = q * 512 + tid;
        *(int4*)(sWf + idx * 8) = *(const int4*)(wf + idx * 8);
    }
    if (tid < N_DIM) sC[tid] = cg[tid];
    else if (tid < 2 * N_DIM) sW1[tid - N_DIM] = w1g[tid - N_DIM];
    __syncthreads();   // the ONLY barrier

    // ones fragment for row-sum MFMA
    union { unsigned short u[8]; bf16x8 f; } onesu;
    #pragma unroll
    for (int r = 0; r < 8; ++r) onesu.u[r] = 0x3F80;   // bf16 1.0
    const bf16x8 ones = onesu.f;

    unsigned short* sAw = sA[wave];
    float* stage = (float*)sAw;            // [8][ST_STRIDE] f32, 4352B region
    float* op = out + waveRow0 * N_DIM;

    for (int t = 0; t < T_PER_WAVE; ++t) {
        // --- pack RAW x -> bf16 -> LDS (no stats dependency) ---
        #pragma unroll
        for (int i = 0; i < 8; ++i) {
            const f32x4 w4 = v[i];
            ushort4 pk;
            pk.x = f2bf(w4[0]); pk.y = f2bf(w4[1]);
            pk.z = f2bf(w4[2]); pk.w = f2bf(w4[3]);
            *(ushort4*)(sAw + (2 * i + h) * SA_STRIDE + s * 4) = pk;
        }

        // --- prefetch next tile (v dead now); nt loads ---
        if (t + 1 < T_PER_WAVE) {
            const f32x4* xn = xp + (size_t)(t + 1) * 16 * (K_DIM / 4);
            #pragma unroll
            for (int i = 0; i < 8; ++i)
                v[i] = __builtin_nontemporal_load(xn + (2 * i + h) * (K_DIM / 4));
        }

        // cross-lane LDS write->read: compiler fence (per-thread AA would reorder)
        asm volatile("" ::: "memory");

        // --- A-fragments: lane (m,kg) reads row m, k = kt*32+kg*8 ---
        bf16x8 af[4];
        #pragma unroll
        for (int kt = 0; kt < 4; ++kt)
            af[kt] = *(const bf16x8*)(sAw + m * SA_STRIDE + kt * 32 + kg * 8);

        // --- MFMA: G = x@W' (8 n-tiles) + row-sum (ones) + Gram (sumsq diag) ---
        f32x4 acc[8] = {};
        f32x4 asum = {0.f, 0.f, 0.f, 0.f};
        f32x4 gram = {0.f, 0.f, 0.f, 0.f};
        #pragma unroll
        for (int kt = 0; kt < 4; ++kt) {
            asum = __builtin_amdgcn_mfma_f32_16x16x32_bf16(ones, af[kt], asum, 0, 0, 0);
            gram = __builtin_amdgcn_mfma_f32_16x16x32_bf16(af[kt], af[kt], gram, 0, 0, 0);
            #pragma unroll
            for (int nt = 0; nt < 8; ++nt) {
                const bf16x8 bw = *(const bf16x8*)(sWf + ((nt * 4 + kt) * 64 + lane) * 8);
                acc[nt] = __builtin_amdgcn_mfma_f32_16x16x32_bf16(bw, af[kt], acc[nt], 0, 0, 0);
            }
        }

        // --- row stats: sum per-lane free; sumsq = Gram diag via 1 shuffle ---
        const float dval = (m & 2) ? ((m & 1) ? gram[3] : gram[2])
                                   : ((m & 1) ? gram[1] : gram[0]);
        const float ss   = __shfl(dval, ((m >> 2) << 4) | m);
        const float sum  = asum[0];
        const float mean = sum * 0.0078125f;                          // /128
        const float var  = fmaxf(ss * 0.0078125f - mean * mean, 0.f);
        const float a    = rsqrtf(var + 1e-5f);                       // rstd
        const float b    = -a * mean;

        // --- scale: y = a*G + b*w1 + c (broadcast ds_reads, conflict-free) ---
        #pragma unroll
        for (int nt = 0; nt < 8; ++nt) {
            const f32x4 w1v = *(const f32x4*)&sW1[nt * 16 + kg * 4];
            const f32x4 cv  = *(const f32x4*)&sC [nt * 16 + kg * 4];
            #pragma unroll
            for (int i = 0; i < 4; ++i)
                acc[nt][i] = fmaf(a, acc[nt][i], fmaf(b, w1v[i], cv[i]));
        }

        // --- epilogue: transpose acc through wave-private LDS -> 1KB bursts,
        //     nontemporal stores (out is never re-read) ---
        #pragma unroll
        for (int half = 0; half < 2; ++half) {
            if ((m >> 3) == half) {
                const int lr = m & 7;
                #pragma unroll
                for (int nt = 0; nt < 8; ++nt)
                    *(f32x4*)(stage + lr * ST_STRIDE + nt * 16 + kg * 4) = acc[nt];
            }
            asm volatile("" ::: "memory");   // writes (all lanes) before reads
            #pragma unroll
            for (int j = 0; j < 4; ++j) {
                const int lr = j * 2 + h;
                const f32x4 row = *(const f32x4*)(stage + lr * ST_STRIDE + s * 4);
                __builtin_nontemporal_store(row,
                    (f32x4*)(op + (size_t)(t * 16 + half * 8 + lr) * N_DIM + s * 4));
            }
            asm volatile("" ::: "memory");   // reads before next writes (WAR)
        }
    }
}

extern "C" void kernel_launch(void* const* d_in, const int* in_sizes, int n_in,
                              void* d_out, int out_size, void* d_ws, size_t ws_size,
                              hipStream_t stream) {
    const float* x   = (const float*)d_in[0];
    const float* lnw = (const float*)d_in[1];
    const float* lnb = (const float*)d_in[2];
    const float* B   = (const float*)d_in[3];
    float* out = (float*)d_out;

    unsigned short* wf = (unsigned short*)d_ws;
    float* cg  = (float*)((char*)d_ws + 32768);
    float* w1g = (float*)((char*)d_ws + 32768 + 512);

    hipLaunchKernelGGL(prep_kernel, dim3(8), dim3(256), 0, stream, lnw, lnb, B, wf, cg, w1g);

    const int M = in_sizes[0] / K_DIM;                       // 524288
    const int grid = M / (WAVES * T_PER_WAVE * 16);          // 512 = exactly 2 blocks/CU
    hipLaunchKernelGGL(lnlin_kernel, dim3(grid), dim3(512), 0, stream, x, wf, cg, w1g, out);
}

// Round 13
// 97.805 us; speedup vs baseline: 2.3690x; 1.1527x over previous
//
#include <hip/hip_runtime.h>

// LayerNorm(K=128) + Linear(128x128) fused, fp32 in/out, bf16 MFMA inside.
// Round 13: A/B isolating r11's two-variable change. Keep NONTEMPORAL x
// loads (zero-reuse stream should not allocate in L2); revert out stores to
// NORMAL write-back (stores are 1KB full-line bursts -> L2 write-back merges
// and schedules HBM writes better than nt streaming; the 7.0 TB/s fill
// kernel uses normal stores). Everything else byte-identical to r12
// (112.7us, absmax 0.03125).

#define K_DIM 128
#define N_DIM 128
#define SA_STRIDE 136    // shorts: 272B row stride for x staging (16B-aligned)
#define ST_STRIDE 136    // floats: 544B epilogue stage stride, 16B-aligned
#define T_PER_WAVE 8     // 16-row tiles per wave; 8 waves -> 1024 rows/block
#define WAVES 8

typedef __attribute__((ext_vector_type(8))) short bf16x8;
typedef __attribute__((ext_vector_type(4))) float f32x4;

static __device__ __forceinline__ unsigned short f2bf(float f) {
    union { float ff; unsigned int u; } v; v.ff = f;
    const unsigned int u = v.u;
    return (unsigned short)((u + 0x7fffu + ((u >> 16) & 1u)) >> 16);  // RNE
}

// prep (8 blocks): ws[0,32KB)      = W' = diag(lnw)*B, bf16, MFMA A-frag order
//                  ws[32KB,+512)   = c[n]  = sum_k lnb[k]*B[k][n]   (fp32)
//                  ws[32.5KB,+512) = w1[n] = sum_k lnw[k]*B[k][n]   (fp32)
__global__ void prep_kernel(const float* __restrict__ lnw, const float* __restrict__ lnb,
                            const float* __restrict__ B, unsigned short* __restrict__ wf,
                            float* __restrict__ c, float* __restrict__ w1) {
    __shared__ float pc[16][17];
    __shared__ float pw[16][17];
    const int tid = threadIdx.x;
    const int l   = tid & 63;
    const int kt  = tid >> 6;            // 0..3
    const int b   = blockIdx.x;          // 0..7 == nt
    const int n16 = l & 15;
    const int n   = b * 16 + n16;
    const int k0  = kt * 32 + (l >> 4) * 8;
    const int g   = b * 256 + tid;       // wf slot

    union { unsigned short us[8]; int4 i4; } pk;
    float cacc = 0.f, wacc = 0.f;
    #pragma unroll
    for (int r = 0; r < 8; ++r) {
        const float bv = B[(k0 + r) * N_DIM + n];
        const float wb = bv * lnw[k0 + r];
        pk.us[r] = f2bf(wb);
        cacc += lnb[k0 + r] * bv;
        wacc += wb;
    }
    *(int4*)(wf + (size_t)g * 8) = pk.i4;

    pc[kt * 4 + (l >> 4)][n16] = cacc;
    pw[kt * 4 + (l >> 4)][n16] = wacc;
    __syncthreads();
    if (tid < 32) {
        const int nn = tid & 15;
        float s = 0.f;
        if (tid < 16) {
            #pragma unroll
            for (int q = 0; q < 16; ++q) s += pc[q][nn];
            c[b * 16 + nn] = s;
        } else {
            #pragma unroll
            for (int q = 0; q < 16; ++q) s += pw[q][nn];
            w1[b * 16 + nn] = s;
        }
    }
}

__global__ __launch_bounds__(512, 2) void lnlin_kernel(
    const float* __restrict__ x, const unsigned short* __restrict__ wf,
    const float* __restrict__ cg, const float* __restrict__ w1g,
    float* __restrict__ out)
{
    __shared__ __align__(16) unsigned short sWf[2048 * 8];              // 32KB frag-order W'
    __shared__ __align__(16) unsigned short sA[WAVES][16 * SA_STRIDE];  // wave-private raw-x bf16 / epilogue stage
    __shared__ __align__(16) float sC[N_DIM];                           // c row
    __shared__ __align__(16) float sW1[N_DIM];                          // colsum(W') row

    const int tid  = threadIdx.x;
    const int wave = tid >> 6;
    const int lane = tid & 63;
    const int h    = lane >> 5;   // half-wave: row parity
    const int s    = lane & 31;   // 16B chunk within row
    const int m    = lane & 15;   // MFMA: output row index
    const int kg   = lane >> 4;   // MFMA: k-group / n sub-block

    const size_t waveRow0 = ((size_t)blockIdx.x * WAVES + wave) * (T_PER_WAVE * 16);

    // issue first tile's x loads before staging (independent of LDS); nt: zero reuse
    const f32x4* xp = (const f32x4*)(x + waveRow0 * K_DIM) + s;
    f32x4 v[8];
    #pragma unroll
    for (int i = 0; i < 8; ++i)
        v[i] = __builtin_nontemporal_load(xp + (2 * i + h) * (K_DIM / 4));

    // stage frag-order W' (coalesced 16B -> contiguous ds_write_b128) + c + w1
    #pragma unroll
    for (int q = 0; q < 4; ++q) {
        const int idx = q * 512 + tid;
        *(int4*)(sWf + idx * 8) = *(const int4*)(wf + idx * 8);
    }
    if (tid < N_DIM) sC[tid] = cg[tid];
    else if (tid < 2 * N_DIM) sW1[tid - N_DIM] = w1g[tid - N_DIM];
    __syncthreads();   // the ONLY barrier

    // ones fragment for row-sum MFMA
    union { unsigned short u[8]; bf16x8 f; } onesu;
    #pragma unroll
    for (int r = 0; r < 8; ++r) onesu.u[r] = 0x3F80;   // bf16 1.0
    const bf16x8 ones = onesu.f;

    unsigned short* sAw = sA[wave];
    float* stage = (float*)sAw;            // [8][ST_STRIDE] f32, 4352B region
    float* op = out + waveRow0 * N_DIM;

    for (int t = 0; t < T_PER_WAVE; ++t) {
        // --- pack RAW x -> bf16 -> LDS (no stats dependency) ---
        #pragma unroll
        for (int i = 0; i < 8; ++i) {
            const f32x4 w4 = v[i];
            ushort4 pk;
            pk.x = f2bf(w4[0]); pk.y = f2bf(w4[1]);
            pk.z = f2bf(w4[2]); pk.w = f2bf(w4[3]);
            *(ushort4*)(sAw + (2 * i + h) * SA_STRIDE + s * 4) = pk;
        }

        // --- prefetch next tile (v dead now); nt loads ---
        if (t + 1 < T_PER_WAVE) {
            const f32x4* xn = xp + (size_t)(t + 1) * 16 * (K_DIM / 4);
            #pragma unroll
            for (int i = 0; i < 8; ++i)
                v[i] = __builtin_nontemporal_load(xn + (2 * i + h) * (K_DIM / 4));
        }

        // cross-lane LDS write->read: compiler fence (per-thread AA would reorder)
        asm volatile("" ::: "memory");

        // --- A-fragments: lane (m,kg) reads row m, k = kt*32+kg*8 ---
        bf16x8 af[4];
        #pragma unroll
        for (int kt = 0; kt < 4; ++kt)
            af[kt] = *(const bf16x8*)(sAw + m * SA_STRIDE + kt * 32 + kg * 8);

        // --- MFMA: G = x@W' (8 n-tiles) + row-sum (ones) + Gram (sumsq diag) ---
        f32x4 acc[8] = {};
        f32x4 asum = {0.f, 0.f, 0.f, 0.f};
        f32x4 gram = {0.f, 0.f, 0.f, 0.f};
        #pragma unroll
        for (int kt = 0; kt < 4; ++kt) {
            asum = __builtin_amdgcn_mfma_f32_16x16x32_bf16(ones, af[kt], asum, 0, 0, 0);
            gram = __builtin_amdgcn_mfma_f32_16x16x32_bf16(af[kt], af[kt], gram, 0, 0, 0);
            #pragma unroll
            for (int nt = 0; nt < 8; ++nt) {
                const bf16x8 bw = *(const bf16x8*)(sWf + ((nt * 4 + kt) * 64 + lane) * 8);
                acc[nt] = __builtin_amdgcn_mfma_f32_16x16x32_bf16(bw, af[kt], acc[nt], 0, 0, 0);
            }
        }

        // --- row stats: sum per-lane free; sumsq = Gram diag via 1 shuffle ---
        const float dval = (m & 2) ? ((m & 1) ? gram[3] : gram[2])
                                   : ((m & 1) ? gram[1] : gram[0]);
        const float ss   = __shfl(dval, ((m >> 2) << 4) | m);
        const float sum  = asum[0];
        const float mean = sum * 0.0078125f;                          // /128
        const float var  = fmaxf(ss * 0.0078125f - mean * mean, 0.f);
        const float a    = rsqrtf(var + 1e-5f);                       // rstd
        const float b    = -a * mean;

        // --- scale: y = a*G + b*w1 + c (broadcast ds_reads, conflict-free) ---
        #pragma unroll
        for (int nt = 0; nt < 8; ++nt) {
            const f32x4 w1v = *(const f32x4*)&sW1[nt * 16 + kg * 4];
            const f32x4 cv  = *(const f32x4*)&sC [nt * 16 + kg * 4];
            #pragma unroll
            for (int i = 0; i < 4; ++i)
                acc[nt][i] = fmaf(a, acc[nt][i], fmaf(b, w1v[i], cv[i]));
        }

        // --- epilogue: transpose acc through wave-private LDS -> 1KB bursts,
        //     NORMAL stores (L2 write-back merges full lines; A/B vs r12 nt) ---
        #pragma unroll
        for (int half = 0; half < 2; ++half) {
            if ((m >> 3) == half) {
                const int lr = m & 7;
                #pragma unroll
                for (int nt = 0; nt < 8; ++nt)
                    *(f32x4*)(stage + lr * ST_STRIDE + nt * 16 + kg * 4) = acc[nt];
            }
            asm volatile("" ::: "memory");   // writes (all lanes) before reads
            #pragma unroll
            for (int j = 0; j < 4; ++j) {
                const int lr = j * 2 + h;
                const f32x4 row = *(const f32x4*)(stage + lr * ST_STRIDE + s * 4);
                *(f32x4*)(op + (size_t)(t * 16 + half * 8 + lr) * N_DIM + s * 4) = row;
            }
            asm volatile("" ::: "memory");   // reads before next writes (WAR)
        }
    }
}

extern "C" void kernel_launch(void* const* d_in, const int* in_sizes, int n_in,
                              void* d_out, int out_size, void* d_ws, size_t ws_size,
                              hipStream_t stream) {
    const float* x   = (const float*)d_in[0];
    const float* lnw = (const float*)d_in[1];
    const float* lnb = (const float*)d_in[2];
    const float* B   = (const float*)d_in[3];
    float* out = (float*)d_out;

    unsigned short* wf = (unsigned short*)d_ws;
    float* cg  = (float*)((char*)d_ws + 32768);
    float* w1g = (float*)((char*)d_ws + 32768 + 512);

    hipLaunchKernelGGL(prep_kernel, dim3(8), dim3(256), 0, stream, lnw, lnb, B, wf, cg, w1g);

    const int M = in_sizes[0] / K_DIM;                       // 524288
    const int grid = M / (WAVES * T_PER_WAVE * 16);          // 512 = exactly 2 blocks/CU
    hipLaunchKernelGGL(lnlin_kernel, dim3(grid), dim3(512), 0, stream, x, wf, cg, w1g, out);
}

// Round 14
// 95.655 us; speedup vs baseline: 2.4222x; 1.0225x over previous
//
#include <hip/hip_runtime.h>

// LayerNorm(K=128) + Linear(128x128) fused, fp32 in/out, bf16 MFMA inside.
// Round 14: single-kernel version of r13 (97.8us). The prep kernel
// (W'/c/w1 build) is folded into each block's prologue: B is 64KB and
// L2-resident, so 512 blocks re-deriving W' costs ~32 cached loads/thread,
// overlapped with the first-tile x loads; this removes the prep kernel's
// serial execution + inter-kernel gap (~3-5us) from the timed graph.
// c/w1 partials reduce through the sA region (dead until the barrier).
// Main loop byte-identical to r13: nt x loads, normal burst stores,
// barrier-free, frag-order W', stats-from-MFMA (ones + Gram diag).

#define K_DIM 128
#define N_DIM 128
#define SA_STRIDE 136    // shorts: 272B row stride for x staging (16B-aligned)
#define ST_STRIDE 136    // floats: 544B epilogue stage stride, 16B-aligned
#define T_PER_WAVE 8     // 16-row tiles per wave; 8 waves -> 1024 rows/block
#define WAVES 8

typedef __attribute__((ext_vector_type(8))) short bf16x8;
typedef __attribute__((ext_vector_type(4))) float f32x4;

static __device__ __forceinline__ unsigned short f2bf(float f) {
    union { float ff; unsigned int u; } v; v.ff = f;
    const unsigned int u = v.u;
    return (unsigned short)((u + 0x7fffu + ((u >> 16) & 1u)) >> 16);  // RNE
}

__global__ __launch_bounds__(512, 2) void lnlin_kernel(
    const float* __restrict__ x, const float* __restrict__ lnw,
    const float* __restrict__ lnb, const float* __restrict__ B,
    float* __restrict__ out)
{
    __shared__ __align__(16) unsigned short sWf[2048 * 8];              // 32KB frag-order W'
    __shared__ __align__(16) unsigned short sA[WAVES][16 * SA_STRIDE];  // prologue reduce / x staging / store stage
    __shared__ __align__(16) float sC[N_DIM];                           // c row
    __shared__ __align__(16) float sW1[N_DIM];                          // colsum(W') row

    const int tid  = threadIdx.x;
    const int wave = tid >> 6;
    const int lane = tid & 63;
    const int h    = lane >> 5;   // half-wave: row parity
    const int s    = lane & 31;   // 16B chunk within row
    const int m    = lane & 15;   // MFMA: output row index
    const int kg   = lane >> 4;   // MFMA: k-group / n sub-block

    const size_t waveRow0 = ((size_t)blockIdx.x * WAVES + wave) * (T_PER_WAVE * 16);

    // issue first tile's x loads FIRST (independent of all LDS/prologue work)
    const f32x4* xp = (const f32x4*)(x + waveRow0 * K_DIM) + s;
    f32x4 v[8];
    #pragma unroll
    for (int i = 0; i < 8; ++i)
        v[i] = __builtin_nontemporal_load(xp + (2 * i + h) * (K_DIM / 4));

    // --- prologue: build W' = diag(lnw)*B in MFMA frag order -> sWf,
    //     and c = lnb^T B, w1 = colsum(W') via partials in the (dead) sA region ---
    {
        const int l0  = tid & 63;
        const int kt0 = (tid >> 6) & 3;
        const int hi  = tid >> 8;                 // 0/1
        const int n16 = l0 & 15;
        const int lg  = (l0 >> 4) & 3;
        const int k0  = kt0 * 32 + lg * 8;
        const int grp = kt0 * 4 + lg;             // 0..15
        float* pc = (float*)&sA[0][0];            // [16][128] partial c
        float* pw = pc + 2048;                    // [16][128] partial w1 (16KB total <= 34KB region)

        float wk[8], bk[8];
        #pragma unroll
        for (int r = 0; r < 8; ++r) { wk[r] = lnw[k0 + r]; bk[r] = lnb[k0 + r]; }

        #pragma unroll
        for (int q = 0; q < 4; ++q) {
            const int nt  = 2 * q + hi;
            const int n   = nt * 16 + n16;
            const int idx = (nt << 8) | (kt0 << 6) | l0;   // == q*512 + tid
            union { unsigned short us[8]; int4 i4; } pk;
            float cacc = 0.f, wacc = 0.f;
            #pragma unroll
            for (int r = 0; r < 8; ++r) {
                const float bv = B[(k0 + r) * N_DIM + n];
                const float wb = bv * wk[r];
                pk.us[r] = f2bf(wb);
                cacc += bk[r] * bv;
                wacc += wb;
            }
            *(int4*)(sWf + idx * 8) = pk.i4;
            pc[grp * 128 + n] = cacc;
            pw[grp * 128 + n] = wacc;
        }
    }
    __syncthreads();
    if (tid < 128) {
        const float* pc = (const float*)&sA[0][0];
        float acc = 0.f;
        #pragma unroll
        for (int g = 0; g < 16; ++g) acc += pc[g * 128 + tid];
        sC[tid] = acc;
    } else if (tid < 256) {
        const int n = tid - 128;
        const float* pw = (const float*)&sA[0][0] + 2048;
        float acc = 0.f;
        #pragma unroll
        for (int g = 0; g < 16; ++g) acc += pw[g * 128 + n];
        sW1[n] = acc;
    }
    __syncthreads();   // sC/sW1 ready; sA region dead again -> main loop reuses it

    // ones fragment for row-sum MFMA
    union { unsigned short u[8]; bf16x8 f; } onesu;
    #pragma unroll
    for (int r = 0; r < 8; ++r) onesu.u[r] = 0x3F80;   // bf16 1.0
    const bf16x8 ones = onesu.f;

    unsigned short* sAw = sA[wave];
    float* stage = (float*)sAw;            // [8][ST_STRIDE] f32, 4352B region
    float* op = out + waveRow0 * N_DIM;

    for (int t = 0; t < T_PER_WAVE; ++t) {
        // --- pack RAW x -> bf16 -> LDS (no stats dependency) ---
        #pragma unroll
        for (int i = 0; i < 8; ++i) {
            const f32x4 w4 = v[i];
            ushort4 pk;
            pk.x = f2bf(w4[0]); pk.y = f2bf(w4[1]);
            pk.z = f2bf(w4[2]); pk.w = f2bf(w4[3]);
            *(ushort4*)(sAw + (2 * i + h) * SA_STRIDE + s * 4) = pk;
        }

        // --- prefetch next tile (v dead now); nt loads ---
        if (t + 1 < T_PER_WAVE) {
            const f32x4* xn = xp + (size_t)(t + 1) * 16 * (K_DIM / 4);
            #pragma unroll
            for (int i = 0; i < 8; ++i)
                v[i] = __builtin_nontemporal_load(xn + (2 * i + h) * (K_DIM / 4));
        }

        // cross-lane LDS write->read: compiler fence (per-thread AA would reorder)
        asm volatile("" ::: "memory");

        // --- A-fragments: lane (m,kg) reads row m, k = kt*32+kg*8 ---
        bf16x8 af[4];
        #pragma unroll
        for (int kt = 0; kt < 4; ++kt)
            af[kt] = *(const bf16x8*)(sAw + m * SA_STRIDE + kt * 32 + kg * 8);

        // --- MFMA: G = x@W' (8 n-tiles) + row-sum (ones) + Gram (sumsq diag) ---
        f32x4 acc[8] = {};
        f32x4 asum = {0.f, 0.f, 0.f, 0.f};
        f32x4 gram = {0.f, 0.f, 0.f, 0.f};
        #pragma unroll
        for (int kt = 0; kt < 4; ++kt) {
            asum = __builtin_amdgcn_mfma_f32_16x16x32_bf16(ones, af[kt], asum, 0, 0, 0);
            gram = __builtin_amdgcn_mfma_f32_16x16x32_bf16(af[kt], af[kt], gram, 0, 0, 0);
            #pragma unroll
            for (int nt = 0; nt < 8; ++nt) {
                const bf16x8 bw = *(const bf16x8*)(sWf + ((nt * 4 + kt) * 64 + lane) * 8);
                acc[nt] = __builtin_amdgcn_mfma_f32_16x16x32_bf16(bw, af[kt], acc[nt], 0, 0, 0);
            }
        }

        // --- row stats: sum per-lane free; sumsq = Gram diag via 1 shuffle ---
        const float dval = (m & 2) ? ((m & 1) ? gram[3] : gram[2])
                                   : ((m & 1) ? gram[1] : gram[0]);
        const float ss   = __shfl(dval, ((m >> 2) << 4) | m);
        const float sum  = asum[0];
        const float mean = sum * 0.0078125f;                          // /128
        const float var  = fmaxf(ss * 0.0078125f - mean * mean, 0.f);
        const float a    = rsqrtf(var + 1e-5f);                       // rstd
        const float b    = -a * mean;

        // --- scale: y = a*G + b*w1 + c (broadcast ds_reads, conflict-free) ---
        #pragma unroll
        for (int nt = 0; nt < 8; ++nt) {
            const f32x4 w1v = *(const f32x4*)&sW1[nt * 16 + kg * 4];
            const f32x4 cv  = *(const f32x4*)&sC [nt * 16 + kg * 4];
            #pragma unroll
            for (int i = 0; i < 4; ++i)
                acc[nt][i] = fmaf(a, acc[nt][i], fmaf(b, w1v[i], cv[i]));
        }

        // --- epilogue: transpose acc through wave-private LDS -> 1KB bursts,
        //     NORMAL stores (L2 write-back merges full lines) ---
        #pragma unroll
        for (int half = 0; half < 2; ++half) {
            if ((m >> 3) == half) {
                const int lr = m & 7;
                #pragma unroll
                for (int nt = 0; nt < 8; ++nt)
                    *(f32x4*)(stage + lr * ST_STRIDE + nt * 16 + kg * 4) = acc[nt];
            }
            asm volatile("" ::: "memory");   // writes (all lanes) before reads
            #pragma unroll
            for (int j = 0; j < 4; ++j) {
                const int lr = j * 2 + h;
                const f32x4 row = *(const f32x4*)(stage + lr * ST_STRIDE + s * 4);
                *(f32x4*)(op + (size_t)(t * 16 + half * 8 + lr) * N_DIM + s * 4) = row;
            }
            asm volatile("" ::: "memory");   // reads before next writes (WAR)
        }
    }
}

extern "C" void kernel_launch(void* const* d_in, const int* in_sizes, int n_in,
                              void* d_out, int out_size, void* d_ws, size_t ws_size,
                              hipStream_t stream) {
    const float* x   = (const float*)d_in[0];
    const float* lnw = (const float*)d_in[1];
    const float* lnb = (const float*)d_in[2];
    const float* B   = (const float*)d_in[3];
    float* out = (float*)d_out;

    const int M = in_sizes[0] / K_DIM;                       // 524288
    const int grid = M / (WAVES * T_PER_WAVE * 16);          // 512 = exactly 2 blocks/CU
    hipLaunchKernelGGL(lnlin_kernel, dim3(grid), dim3(512), 0, stream,
                       x, lnw, lnb, B, out);
}